// Round 17
// baseline (193.786 us; speedup 1.0000x reference)
//
#include <hip/hip_runtime.h>
#include <hip/hip_bf16.h>

#define B_ 4
#define U_ 16
#define L_ 128
#define H_ 768
#define M_ 256
#define HID_ 150

typedef _Float16 half8 __attribute__((ext_vector_type(8)));
typedef _Float16 half4t __attribute__((ext_vector_type(4)));
typedef float floatx4 __attribute__((ext_vector_type(4)));

// async global->LDS, 16B per lane; lds dest must be wave-uniform base.
__device__ __forceinline__ void gl_lds16(const _Float16* g, _Float16* l)
{
    __builtin_amdgcn_global_load_lds(
        (const __attribute__((address_space(1))) unsigned int*)g,
        (__attribute__((address_space(3))) unsigned int*)l, 16, 0, 0);
}

// ---------------------------------------------------------------------------
// Kernel 0: fused prepack + pool.
//   blocks [0,1540): prepack weights into 16x16 A-frag layout (R16):
//     frag idx = ((k>>5)*NT + (n>>4))*512 + (((n&15)|(((k>>3)&3)<<4))<<3) + (k&7)
//   blocks [1540,1796): masked mean-pool -> f16 (4 rows/block, 64 thr/row).
// ---------------------------------------------------------------------------
__global__ __launch_bounds__(256) void prep_pool_kernel(
    const float* __restrict__ W1, const float* __restrict__ W2,
    const float* __restrict__ b2, const float* __restrict__ W3,
    const float* __restrict__ hidden, const int* __restrict__ sutt,
    const int* __restrict__ sstart, const int* __restrict__ send,
    _Float16* __restrict__ W1cs16, _Float16* __restrict__ W2s16,
    _Float16* __restrict__ W1abs, float2* __restrict__ bw,
    _Float16* __restrict__ pooledh)
{
    if (blockIdx.x >= 1540) {   // ---- pool part ----
        const int bm = (blockIdx.x - 1540) * 4 + (threadIdx.x >> 6);
        const int lane = threadIdx.x & 63;
        const int b  = bm >> 8;
        const int u  = sutt[bm];
        const int st = sstart[bm];
        const int en = send[bm];
        const float inv = 1.0f / (float)(en - st);
        const float* src = hidden + ((size_t)(b * U_ + u) * L_) * H_ + lane * 12;
        float4 s[3];
        #pragma unroll
        for (int q = 0; q < 3; ++q) s[q] = make_float4(0.f, 0.f, 0.f, 0.f);
        for (int l = st; l < en; ++l) {
            const float* p = src + (size_t)l * H_;
            #pragma unroll
            for (int q = 0; q < 3; ++q) {
                float4 v = *(const float4*)(p + q * 4);
                s[q].x += v.x; s[q].y += v.y; s[q].z += v.z; s[q].w += v.w;
            }
        }
        _Float16* gp = pooledh + (size_t)bm * H_ + lane * 12;
        #pragma unroll
        for (int q = 0; q < 3; ++q) {
            half4t hv;
            hv[0] = (_Float16)(s[q].x * inv); hv[1] = (_Float16)(s[q].y * inv);
            hv[2] = (_Float16)(s[q].z * inv); hv[3] = (_Float16)(s[q].w * inv);
            *(half4t*)(gp + q * 4) = hv;
        }
        return;
    }
    // ---- prep part ----
    int idx = blockIdx.x * 256 + threadIdx.x;
    if (blockIdx.x == 0 && threadIdx.x < 160) {
        int n = threadIdx.x;
        bw[n] = (n < HID_) ? make_float2(b2[n], W3[n]) : make_float2(0.f, 0.f);
    }
    if (idx < 122880) {   // W1cs16: idx = k*160 + n (n-inner -> coalesced read)
        int k = idx / 160, n = idx - k * 160;
        float v = (n < HID_) ? W1[(size_t)(2 * H_ + k) * HID_ + n] : 0.f;
        W1cs16[((k >> 5) * 10 + (n >> 4)) * 512 +
               (((n & 15) | (((k >> 3) & 3) << 4)) << 3) + (k & 7)] = (_Float16)v;
        return;
    }
    idx -= 122880;
    if (idx < 25600) {    // W2s16: idx = k*160 + n
        int k = idx / 160, n = idx - k * 160;
        float v = (k < HID_ && n < HID_) ? W2[(size_t)k * HID_ + n] : 0.f;
        W2s16[((k >> 5) * 10 + (n >> 4)) * 512 +
              (((n & 15) | (((k >> 3) & 3) << 4)) << 3) + (k & 7)] = (_Float16)v;
        return;
    }
    idx -= 25600;
    if (idx < 245760) {   // W1abs: idx = k*320 + n
        int k = idx / 320, n = idx - k * 320;
        float v = 0.f;
        if (n < HID_) v = W1[(size_t)k * HID_ + n];
        else if (n >= 160 && n < 160 + HID_) v = W1[(size_t)(H_ + k) * HID_ + (n - 160)];
        W1abs[(k >> 5) * 10240 + (n >> 4) * 512 +
              (((n & 15) | (((k >> 3) & 3) << 4)) << 3) + (k & 7)] = (_Float16)v;
    }
}

// ---------------------------------------------------------------------------
// Kernel 2: hi/hj projection + pooled-j 16x16 B-frag prepack.
//   blocks [0,64): hihj (R11-measured config).
//   blocks [64,448): pjF16 pack (R16-measured).
// ---------------------------------------------------------------------------
__global__ __launch_bounds__(256) void hihj_kernel(
    const _Float16* __restrict__ pooledh, const float* __restrict__ b1,
    const _Float16* __restrict__ W1abs,
    float* __restrict__ hiF, float* __restrict__ hjT,
    _Float16* __restrict__ pjF16)
{
    if (blockIdx.x >= 64) {   // ---- pjF16 pack: 384 blocks x 256 half8s ----
        const int idx = (blockIdx.x - 64) * 256 + threadIdx.x;  // [0, 98304)
        const int g16 = idx / 1536, rem = idx - g16 * 1536;     // 24kc x 64ln
        const int kc = rem >> 6, l = rem & 63;
        const int row = (g16 >> 4) * 256 + (g16 & 15) * 16 + (l & 15);
        const int col = kc * 32 + ((l >> 4) << 3);
        *(half8*)&pjF16[(size_t)idx * 8] =
            *(const half8*)&pooledh[(size_t)row * H_ + col];
        return;
    }
    __shared__ __align__(16) _Float16 spool[16 * 776];
    const int blk = blockIdx.x;
    const int tid = threadIdx.x;
    for (int e = tid; e < 16 * 96; e += 256) {
        int r = e / 96, c = e - r * 96;
        *(half8*)&spool[r * 776 + c * 8] =
            *(const half8*)&pooledh[(size_t)(blk * 16 + r) * H_ + c * 8];
    }
    __syncthreads();

    const int w = tid >> 6, lane = tid & 63;
    const int g = lane >> 4, l15 = lane & 15;
    floatx4 acc[5];
    #pragma unroll
    for (int u5 = 0; u5 < 5; ++u5) acc[u5] = (floatx4){0.f, 0.f, 0.f, 0.f};
    const _Float16* aB = &spool[l15 * 776 + g * 8];
    for (int kc = 0; kc < 24; ++kc) {
        half8 av = *(const half8*)(aB + kc * 32);
        #pragma unroll
        for (int u5 = 0; u5 < 5; ++u5) {
            const int u = w * 5 + u5;
            half8 bv = *(const half8*)(W1abs + (size_t)((kc * 20 + u) * 64 + lane) * 8);
            acc[u5] = __builtin_amdgcn_mfma_f32_16x16x32_f16(av, bv, acc[u5], 0, 0, 0);
        }
    }
    const int row0 = blk * 16 + g * 4;
    #pragma unroll
    for (int u5 = 0; u5 < 5; ++u5) {
        const int n = (w * 5 + u5) * 16 + l15;
        if (n < HID_) {
            float b1v = b1[n];
            #pragma unroll
            for (int r = 0; r < 4; ++r)
                hiF[(size_t)(row0 + r) * 160 + n] = acc[u5][r] + b1v;
        } else if (n >= 160 && n < 160 + HID_) {
            *(float4*)&hjT[(size_t)(n - 160) * 1024 + row0] =
                make_float4(acc[u5][0], acc[u5][1], acc[u5][2], acc[u5][3]);
        }
    }
}

// ---------------------------------------------------------------------------
// Kernel 3: fused pair MLP. R17 = R16 + n-split wave assignment (stage 1).
//   R16 post-mortem: occ 22.5->33% but dur unchanged, MfmaUtil pinned 24% --
//   LDS-read-BW bound: every wave read all 10 W frags (40KB/block-phase).
//   Fix: stage-1 wave = (i-row, n-HALF): reads only its 5 W frags (5KB),
//   computes BOTH j-halves vs them -> block LDS-read 40->20KB/phase, MFMA
//   count unchanged, acc still 5x2x4 = 40 AGPR. h1 becomes per-i [32j][170]
//   (n-half waves write disjoint cols). Stage 2/3 keep R16's (i,jh) split.
// C/D 16x16: col=lane&15 (=j), row=(lane>>4)*4+reg (=n-local). [hihj-verified]
// ---------------------------------------------------------------------------
__global__ __launch_bounds__(256, 4) void pair_mlp_kernel(
    const _Float16* __restrict__ pooledh, const _Float16* __restrict__ pjF16,
    const float* __restrict__ hiF, const float* __restrict__ hjT,
    const _Float16* __restrict__ W1cs16, const _Float16* __restrict__ W2s16,
    const float2* __restrict__ bw, const float* __restrict__ b3,
    float* __restrict__ logits)
{
    __shared__ __align__(16) _Float16 smem[10880];   // 21760 B

    int q = blockIdx.x;
    const int b = q / 576;
    int r = q - b * 576;
    int jt = 0;
    while (r >= 128 - 16 * jt) { r -= 128 - 16 * jt; ++jt; }
    const int p = 16 * jt + r;           // i-pair: i in {2p, 2p+1}
    const int i0 = 2 * p, j0 = jt * 32;
    const int bm = b * M_;
    const int w = threadIdx.x >> 6;      // 4 waves: iw = w>>1, sub = w&1
    const int iw = w >> 1, sub = w & 1;  // stage1: sub = n-half; stage2: j-half
    const int i = i0 + iw;
    const int lane = threadIdx.x & 63;
    const int l15 = lane & 15;
    const int g4 = lane >> 4;            // k-subchunk 0..3

    _Float16* Wb0 = smem;                // [5120] f16 (10240 B)
    _Float16* Wb1 = smem + 5120;
    _Float16* h1i = smem + iw * 5440;    // per-i-row 32x170 f16; aliases W bufs

    const _Float16* pjb0 = pjF16 + (size_t)(b * 16 + jt * 2 + 0) * 12288 + lane * 8;
    const _Float16* pjb1 = pjF16 + (size_t)(b * 16 + jt * 2 + 1) * 12288 + lane * 8;
    const _Float16* pip  = pooledh + (size_t)(bm + i) * H_ + (g4 << 3);

    floatx4 acc1[5][2];                  // [n-tile][jh] = 40 AGPR
    #pragma unroll
    for (int t = 0; t < 5; ++t)
        #pragma unroll
        for (int h = 0; h < 2; ++h) acc1[t][h] = (floatx4){0.f, 0.f, 0.f, 0.f};

    // ---- prologue: stage W chunk 0 (waves 0,1); load A chunk 0 ----
    if (w < 2) {
        const _Float16* gW = W1cs16 + (size_t)(5 * w) * 512 + lane * 8;
        #pragma unroll
        for (int c = 0; c < 5; ++c)
            gl_lds16(gW + c * 512, Wb0 + (5 * w + c) * 512);
    }
    half8 Apj0 = *(const half8*)(pjb0);
    half8 Apj1 = *(const half8*)(pjb1);
    half8 Api  = *(const half8*)(pip);
    __syncthreads();

    // ---- stage 1: K=768, 24 chunks of 32; stage kc+1, compute kc ----
    for (int kc = 0; kc < 24; ++kc) {
        const _Float16* Wcur = ((kc & 1) ? Wb1 : Wb0) + (sub * 5) * 512 + lane * 8;
        _Float16*       Wnxt = (kc & 1) ? Wb0 : Wb1;
        half8 npj0, npj1, npi;
        if (kc < 23) {
            if (w < 2) {
                const _Float16* gW = W1cs16 + (size_t)(kc + 1) * 5120
                                     + (5 * w) * 512 + lane * 8;
                #pragma unroll
                for (int c = 0; c < 5; ++c)
                    gl_lds16(gW + c * 512, Wnxt + (5 * w + c) * 512);
            }
            npj0 = *(const half8*)(pjb0 + (kc + 1) * 512);
            npj1 = *(const half8*)(pjb1 + (kc + 1) * 512);
            npi  = *(const half8*)(pip + (kc + 1) * 32);
        }
        half8 a0 = Api * Apj0;
        half8 a1 = Api * Apj1;
        #pragma unroll
        for (int t = 0; t < 5; ++t) {
            half8 wf = *(const half8*)&Wcur[t * 512];
            acc1[t][0] = __builtin_amdgcn_mfma_f32_16x16x32_f16(wf, a0, acc1[t][0], 0, 0, 0);
            acc1[t][1] = __builtin_amdgcn_mfma_f32_16x16x32_f16(wf, a1, acc1[t][1], 0, 0, 0);
        }
        if (kc < 23) { Apj0 = npj0; Apj1 = npj1; Api = npi; }
        __syncthreads();   // drains vmcnt (staged W); gates dbuf swap
    }
    // After final barrier all waves done with W bufs -> h1 may alias.

    // ---- epilogue 1: h1 = relu(acc + hiF + hjT) -> per-i LDS [32j][170] ----
    #pragma unroll
    for (int t = 0; t < 5; ++t) {
        const int nb = sub * 80 + t * 16 + (g4 << 2);
        float4 hiv = *(const float4*)&hiF[(size_t)(bm + i) * 160 + nb];
        #pragma unroll
        for (int h = 0; h < 2; ++h) {
            const int jcol = bm + j0 + h * 16 + l15;
            float hj0 = hjT[(size_t)(nb + 0) * 1024 + jcol];
            float hj1 = hjT[(size_t)(nb + 1) * 1024 + jcol];
            float hj2 = hjT[(size_t)(nb + 2) * 1024 + jcol];
            float hj3 = hjT[(size_t)(nb + 3) * 1024 + jcol];
            half4t hv;
            hv[0] = (_Float16)fmaxf(acc1[t][h][0] + hiv.x + hj0, 0.f);
            hv[1] = (_Float16)fmaxf(acc1[t][h][1] + hiv.y + hj1, 0.f);
            hv[2] = (_Float16)fmaxf(acc1[t][h][2] + hiv.z + hj2, 0.f);
            hv[3] = (_Float16)fmaxf(acc1[t][h][3] + hiv.w + hj3, 0.f);
            *(half4t*)&h1i[(h * 16 + l15) * 170 + nb] = hv;
        }
    }
    __syncthreads();

    // ---- stage 2: wave = (iw, jh=sub). acc2 = W2 @ h1 (K=160, 5 chunks) ----
    const float b3v = b3[0];
    floatx4 acc2[10];
    #pragma unroll
    for (int t2 = 0; t2 < 10; ++t2) acc2[t2] = (floatx4){0.f, 0.f, 0.f, 0.f};
    for (int kc2 = 0; kc2 < 5; ++kc2) {
        half8 hb = *(const half8*)&h1i[(sub * 16 + l15) * 170 + kc2 * 32 + (g4 << 3)];
        #pragma unroll
        for (int t2 = 0; t2 < 10; ++t2) {
            half8 wf = *(const half8*)(W2s16 + (size_t)(kc2 * 10 + t2) * 512 + lane * 8);
            acc2[t2] = __builtin_amdgcn_mfma_f32_16x16x32_f16(wf, hb, acc2[t2], 0, 0, 0);
        }
    }

    // ---- stage 3: s = relu(acc2 + b2) . W3, cross-k-group reduce, write ----
    float sown = 0.f;
    #pragma unroll
    for (int t2 = 0; t2 < 10; ++t2) {
        const int n2 = t2 * 16 + (g4 << 2);
        float4 bw01 = *(const float4*)&bw[n2];
        float4 bw23 = *(const float4*)&bw[n2 + 2];
        sown += fmaxf(acc2[t2][0] + bw01.x, 0.f) * bw01.y;
        sown += fmaxf(acc2[t2][1] + bw01.z, 0.f) * bw01.w;
        sown += fmaxf(acc2[t2][2] + bw23.x, 0.f) * bw23.y;
        sown += fmaxf(acc2[t2][3] + bw23.z, 0.f) * bw23.w;
    }
    float s = sown;
    s += __shfl_xor(s, 16);
    s += __shfl_xor(s, 32);
    const int j = j0 + sub * 16 + l15;
    if (lane < 16 && j < i)
        logits[(size_t)(bm + i) * M_ + j] = s + b3v;
}

// ---------------------------------------------------------------------------
// Kernel 4: loss. 1 wave/row, shuffle-only (no LDS, no barriers).
// ---------------------------------------------------------------------------
__global__ __launch_bounds__(64) void loss_kernel(
    const float* __restrict__ logits, const float* __restrict__ labels,
    float* __restrict__ out)
{
    const int bm = blockIdx.x;
    const int i  = bm & (M_ - 1);
    const int lane = threadIdx.x;

    float val[4];
    #pragma unroll
    for (int qq = 0; qq < 4; ++qq) {
        const int j = qq * 64 + lane;
        val[qq] = (j < i) ? logits[(size_t)bm * M_ + j]
                          : ((j == i) ? 0.0f : -1e30f);
    }
    float m = fmaxf(fmaxf(val[0], val[1]), fmaxf(val[2], val[3]));
    #pragma unroll
    for (int off = 32; off >= 1; off >>= 1) m = fmaxf(m, __shfl_xor(m, off));

    float s = 0.f;
    float e[4];
    #pragma unroll
    for (int qq = 0; qq < 4; ++qq) {
        const int j = qq * 64 + lane;
        e[qq] = (j <= i) ? expf(val[qq] - m) : 0.0f;
        s += e[qq];
    }
    #pragma unroll
    for (int off = 32; off >= 1; off >>= 1) s += __shfl_xor(s, off);
    const float inv_s = 1.0f / s;

    float rs = 0.f;
    #pragma unroll
    for (int qq = 0; qq < 4; ++qq) {
        const int j = qq * 64 + lane;
        float prob = (j <= i) ? (e[qq] * inv_s) : -1000.0f;
        float tv = prob * labels[(size_t)bm * M_ + j];
        rs += fminf(fmaxf(tv, 1e-8f), 1.0f - 1e-8f);
    }
    #pragma unroll
    for (int off = 32; off >= 1; off >>= 1) rs += __shfl_xor(rs, off);

    if (lane == 0) atomicAdd(out, -logf(rs));
}

// ---------------------------------------------------------------------------
extern "C" void kernel_launch(void* const* d_in, const int* in_sizes, int n_in,
                              void* d_out, int out_size, void* d_ws, size_t ws_size,
                              hipStream_t stream)
{
    const float* hidden = (const float*)d_in[0];
    const int*   sutt   = (const int*)d_in[1];
    const int*   sstart = (const int*)d_in[2];
    const int*   send   = (const int*)d_in[3];
    const float* labels = (const float*)d_in[4];
    const float* W1     = (const float*)d_in[5];
    const float* b1     = (const float*)d_in[6];
    const float* W2     = (const float*)d_in[7];
    const float* b2     = (const float*)d_in[8];
    const float* W3     = (const float*)d_in[9];
    const float* b3     = (const float*)d_in[10];

    float* ws = (float*)d_ws;
    float*    hiF     = ws;                          // [1024][160]
    float*    hjT     = ws + 163840;                 // [160][1024]
    float*    logits  = ws + 327680;                 // 262144
    float2*   bw      = (float2*)(ws + 589824);      // 160 float2
    _Float16* pooledh = (_Float16*)(ws + 590144);    // 786432 f16
    _Float16* W1cs16  = (_Float16*)(ws + 983360);    // 122880 f16
    _Float16* W2s16   = (_Float16*)(ws + 1106240);   // 25600 f16
    _Float16* W1abs   = (_Float16*)(ws + 1119040);   // 245760 f16
    _Float16* pjF16   = (_Float16*)(ws + 1241920);   // 786432 f16 (1.5 MB)
    float* out = (float*)d_out;

    hipMemsetAsync(d_out, 0, sizeof(float), stream);

    prep_pool_kernel<<<dim3(1796), 256, 0, stream>>>(
        W1, W2, b2, W3, hidden, sutt, sstart, send,
        W1cs16, W2s16, W1abs, bw, pooledh);
    hihj_kernel<<<dim3(448), 256, 0, stream>>>(pooledh, b1, W1abs,
                                               hiF, hjT, pjF16);
    pair_mlp_kernel<<<dim3(576 * B_), 256, 0, stream>>>(pooledh, pjF16, hiF, hjT,
                                                        W1cs16, W2s16, bw, b3, logits);
    loss_kernel<<<dim3(B_ * M_), 64, 0, stream>>>(logits, labels, out);
}

// Round 18
// 190.203 us; speedup vs baseline: 1.0188x; 1.0188x over previous
//
#include <hip/hip_runtime.h>
#include <hip/hip_bf16.h>

#define B_ 4
#define U_ 16
#define L_ 128
#define H_ 768
#define M_ 256
#define HID_ 150

typedef _Float16 half8 __attribute__((ext_vector_type(8)));
typedef _Float16 half4t __attribute__((ext_vector_type(4)));
typedef float floatx4 __attribute__((ext_vector_type(4)));

// async global->LDS, 16B per lane; lds dest must be wave-uniform base.
__device__ __forceinline__ void gl_lds16(const _Float16* g, _Float16* l)
{
    __builtin_amdgcn_global_load_lds(
        (const __attribute__((address_space(1))) unsigned int*)g,
        (__attribute__((address_space(3))) unsigned int*)l, 16, 0, 0);
}

// ---------------------------------------------------------------------------
// Kernel 0: fused prepack + pool.
//   blocks [0,1540): prepack weights into 16x16 A-frag layout (R16):
//     frag idx = ((k>>5)*NT + (n>>4))*512 + (((n&15)|(((k>>3)&3)<<4))<<3) + (k&7)
//   blocks [1540,1796): masked mean-pool -> f16 (4 rows/block, 64 thr/row).
// ---------------------------------------------------------------------------
__global__ __launch_bounds__(256) void prep_pool_kernel(
    const float* __restrict__ W1, const float* __restrict__ W2,
    const float* __restrict__ b2, const float* __restrict__ W3,
    const float* __restrict__ hidden, const int* __restrict__ sutt,
    const int* __restrict__ sstart, const int* __restrict__ send,
    _Float16* __restrict__ W1cs16, _Float16* __restrict__ W2s16,
    _Float16* __restrict__ W1abs, float2* __restrict__ bw,
    _Float16* __restrict__ pooledh)
{
    if (blockIdx.x >= 1540) {   // ---- pool part ----
        const int bm = (blockIdx.x - 1540) * 4 + (threadIdx.x >> 6);
        const int lane = threadIdx.x & 63;
        const int b  = bm >> 8;
        const int u  = sutt[bm];
        const int st = sstart[bm];
        const int en = send[bm];
        const float inv = 1.0f / (float)(en - st);
        const float* src = hidden + ((size_t)(b * U_ + u) * L_) * H_ + lane * 12;
        float4 s[3];
        #pragma unroll
        for (int q = 0; q < 3; ++q) s[q] = make_float4(0.f, 0.f, 0.f, 0.f);
        for (int l = st; l < en; ++l) {
            const float* p = src + (size_t)l * H_;
            #pragma unroll
            for (int q = 0; q < 3; ++q) {
                float4 v = *(const float4*)(p + q * 4);
                s[q].x += v.x; s[q].y += v.y; s[q].z += v.z; s[q].w += v.w;
            }
        }
        _Float16* gp = pooledh + (size_t)bm * H_ + lane * 12;
        #pragma unroll
        for (int q = 0; q < 3; ++q) {
            half4t hv;
            hv[0] = (_Float16)(s[q].x * inv); hv[1] = (_Float16)(s[q].y * inv);
            hv[2] = (_Float16)(s[q].z * inv); hv[3] = (_Float16)(s[q].w * inv);
            *(half4t*)(gp + q * 4) = hv;
        }
        return;
    }
    // ---- prep part ----
    int idx = blockIdx.x * 256 + threadIdx.x;
    if (blockIdx.x == 0 && threadIdx.x < 160) {
        int n = threadIdx.x;
        bw[n] = (n < HID_) ? make_float2(b2[n], W3[n]) : make_float2(0.f, 0.f);
    }
    if (idx < 122880) {   // W1cs16: idx = k*160 + n (n-inner -> coalesced read)
        int k = idx / 160, n = idx - k * 160;
        float v = (n < HID_) ? W1[(size_t)(2 * H_ + k) * HID_ + n] : 0.f;
        W1cs16[((k >> 5) * 10 + (n >> 4)) * 512 +
               (((n & 15) | (((k >> 3) & 3) << 4)) << 3) + (k & 7)] = (_Float16)v;
        return;
    }
    idx -= 122880;
    if (idx < 25600) {    // W2s16: idx = k*160 + n
        int k = idx / 160, n = idx - k * 160;
        float v = (k < HID_ && n < HID_) ? W2[(size_t)k * HID_ + n] : 0.f;
        W2s16[((k >> 5) * 10 + (n >> 4)) * 512 +
              (((n & 15) | (((k >> 3) & 3) << 4)) << 3) + (k & 7)] = (_Float16)v;
        return;
    }
    idx -= 25600;
    if (idx < 245760) {   // W1abs: idx = k*320 + n
        int k = idx / 320, n = idx - k * 320;
        float v = 0.f;
        if (n < HID_) v = W1[(size_t)k * HID_ + n];
        else if (n >= 160 && n < 160 + HID_) v = W1[(size_t)(H_ + k) * HID_ + (n - 160)];
        W1abs[(k >> 5) * 10240 + (n >> 4) * 512 +
              (((n & 15) | (((k >> 3) & 3) << 4)) << 3) + (k & 7)] = (_Float16)v;
    }
}

// ---------------------------------------------------------------------------
// Kernel 2: hi/hj projection + pooled-j 16x16 B-frag prepack.
//   blocks [0,64): hihj (R11-measured config).
//   blocks [64,448): pjF16 pack (R16-measured).
// ---------------------------------------------------------------------------
__global__ __launch_bounds__(256) void hihj_kernel(
    const _Float16* __restrict__ pooledh, const float* __restrict__ b1,
    const _Float16* __restrict__ W1abs,
    float* __restrict__ hiF, float* __restrict__ hjT,
    _Float16* __restrict__ pjF16)
{
    if (blockIdx.x >= 64) {   // ---- pjF16 pack: 384 blocks x 256 half8s ----
        const int idx = (blockIdx.x - 64) * 256 + threadIdx.x;  // [0, 98304)
        const int g16 = idx / 1536, rem = idx - g16 * 1536;     // 24kc x 64ln
        const int kc = rem >> 6, l = rem & 63;
        const int row = (g16 >> 4) * 256 + (g16 & 15) * 16 + (l & 15);
        const int col = kc * 32 + ((l >> 4) << 3);
        *(half8*)&pjF16[(size_t)idx * 8] =
            *(const half8*)&pooledh[(size_t)row * H_ + col];
        return;
    }
    __shared__ __align__(16) _Float16 spool[16 * 776];
    const int blk = blockIdx.x;
    const int tid = threadIdx.x;
    for (int e = tid; e < 16 * 96; e += 256) {
        int r = e / 96, c = e - r * 96;
        *(half8*)&spool[r * 776 + c * 8] =
            *(const half8*)&pooledh[(size_t)(blk * 16 + r) * H_ + c * 8];
    }
    __syncthreads();

    const int w = tid >> 6, lane = tid & 63;
    const int g = lane >> 4, l15 = lane & 15;
    floatx4 acc[5];
    #pragma unroll
    for (int u5 = 0; u5 < 5; ++u5) acc[u5] = (floatx4){0.f, 0.f, 0.f, 0.f};
    const _Float16* aB = &spool[l15 * 776 + g * 8];
    for (int kc = 0; kc < 24; ++kc) {
        half8 av = *(const half8*)(aB + kc * 32);
        #pragma unroll
        for (int u5 = 0; u5 < 5; ++u5) {
            const int u = w * 5 + u5;
            half8 bv = *(const half8*)(W1abs + (size_t)((kc * 20 + u) * 64 + lane) * 8);
            acc[u5] = __builtin_amdgcn_mfma_f32_16x16x32_f16(av, bv, acc[u5], 0, 0, 0);
        }
    }
    const int row0 = blk * 16 + g * 4;
    #pragma unroll
    for (int u5 = 0; u5 < 5; ++u5) {
        const int n = (w * 5 + u5) * 16 + l15;
        if (n < HID_) {
            float b1v = b1[n];
            #pragma unroll
            for (int r = 0; r < 4; ++r)
                hiF[(size_t)(row0 + r) * 160 + n] = acc[u5][r] + b1v;
        } else if (n >= 160 && n < 160 + HID_) {
            *(float4*)&hjT[(size_t)(n - 160) * 1024 + row0] =
                make_float4(acc[u5][0], acc[u5][1], acc[u5][2], acc[u5][3]);
        }
    }
}

// ---------------------------------------------------------------------------
// Kernel 3: fused pair MLP. R18 = revert to measured-best R16 (76.9us).
//   R17's n-split (halved LDS reads) REGRESSED to 83.3us -> LDS-BW theory
//   refuted. Family bracketing complete: per-phase cost is a serial
//   ds_read->MFMA chain + phase-boundary latency, insensitive to occupancy
//   (R16), barrier semantics (R10), LDS traffic (R17), register tier
//   (R6/R9/R11), phase size (R7). 76.9us = this formulation's floor.
// C/D 16x16: col=lane&15 (=j), row=(lane>>4)*4+reg (=n-local). [hihj-verified]
// ---------------------------------------------------------------------------
__global__ __launch_bounds__(256, 4) void pair_mlp_kernel(
    const _Float16* __restrict__ pooledh, const _Float16* __restrict__ pjF16,
    const float* __restrict__ hiF, const float* __restrict__ hjT,
    const _Float16* __restrict__ W1cs16, const _Float16* __restrict__ W2s16,
    const float2* __restrict__ bw, const float* __restrict__ b3,
    float* __restrict__ logits)
{
    __shared__ __align__(16) _Float16 smem[10880];   // 21760 B

    int q = blockIdx.x;
    const int b = q / 576;
    int r = q - b * 576;
    int jt = 0;
    while (r >= 128 - 16 * jt) { r -= 128 - 16 * jt; ++jt; }
    const int p = 16 * jt + r;           // i-pair: i in {2p, 2p+1}
    const int i0 = 2 * p, j0 = jt * 32;
    const int bm = b * M_;
    const int w = threadIdx.x >> 6;      // 4 waves: iw = w>>1, jh = w&1
    const int iw = w >> 1, jh = w & 1;
    const int i = i0 + iw;
    const int lane = threadIdx.x & 63;
    const int l15 = lane & 15;
    const int g4 = lane >> 4;            // k-subchunk 0..3

    _Float16* Wb0 = smem;                // [5120] f16 (10240 B)
    _Float16* Wb1 = smem + 5120;
    _Float16* h1w = smem + w * 2720;     // per-wave 16x170 f16; aliases W bufs

    const _Float16* pjb = pjF16 + (size_t)(b * 16 + jt * 2 + jh) * 12288 + lane * 8;
    const _Float16* pip = pooledh + (size_t)(bm + i) * H_ + (g4 << 3);

    floatx4 acc1[10];                    // 40 AGPR
    #pragma unroll
    for (int t = 0; t < 10; ++t) acc1[t] = (floatx4){0.f, 0.f, 0.f, 0.f};

    // ---- prologue: stage W chunk 0 (waves 0,1); load A chunk 0 ----
    if (w < 2) {
        const _Float16* gW = W1cs16 + (size_t)(5 * w) * 512 + lane * 8;
        #pragma unroll
        for (int c = 0; c < 5; ++c)
            gl_lds16(gW + c * 512, Wb0 + (5 * w + c) * 512);
    }
    half8 Apj = *(const half8*)(pjb);
    half8 Api = *(const half8*)(pip);
    __syncthreads();

    // ---- stage 1: K=768, 24 chunks of 32; stage kc+1, compute kc ----
    for (int kc = 0; kc < 24; ++kc) {
        const _Float16* Wcur = (kc & 1) ? Wb1 : Wb0;
        _Float16*       Wnxt = (kc & 1) ? Wb0 : Wb1;
        half8 npj, npi;
        if (kc < 23) {
            if (w < 2) {
                const _Float16* gW = W1cs16 + (size_t)(kc + 1) * 5120
                                     + (5 * w) * 512 + lane * 8;
                #pragma unroll
                for (int c = 0; c < 5; ++c)
                    gl_lds16(gW + c * 512, Wnxt + (5 * w + c) * 512);
            }
            npj = *(const half8*)(pjb + (kc + 1) * 512);
            npi = *(const half8*)(pip + (kc + 1) * 32);
        }
        half8 a = Api * Apj;
        #pragma unroll
        for (int t = 0; t < 10; ++t) {
            half8 wf = *(const half8*)&Wcur[t * 512 + lane * 8];
            acc1[t] = __builtin_amdgcn_mfma_f32_16x16x32_f16(wf, a, acc1[t], 0, 0, 0);
        }
        if (kc < 23) { Apj = npj; Api = npi; }
        __syncthreads();   // drains vmcnt (staged W); gates dbuf swap
    }
    // After final barrier all waves done with W bufs -> h1 may alias.

    // ---- epilogue 1: h1 = relu(acc + hiF + hjT) -> per-wave LDS ----
    const int j = j0 + jh * 16 + l15;
    const int jcol = bm + j;
    #pragma unroll
    for (int t = 0; t < 10; ++t) {
        const int nb = t * 16 + (g4 << 2);
        float hj0 = hjT[(size_t)(nb + 0) * 1024 + jcol];
        float hj1 = hjT[(size_t)(nb + 1) * 1024 + jcol];
        float hj2 = hjT[(size_t)(nb + 2) * 1024 + jcol];
        float hj3 = hjT[(size_t)(nb + 3) * 1024 + jcol];
        float4 hiv = *(const float4*)&hiF[(size_t)(bm + i) * 160 + nb];
        half4t hv;
        hv[0] = (_Float16)fmaxf(acc1[t][0] + hiv.x + hj0, 0.f);
        hv[1] = (_Float16)fmaxf(acc1[t][1] + hiv.y + hj1, 0.f);
        hv[2] = (_Float16)fmaxf(acc1[t][2] + hiv.z + hj2, 0.f);
        hv[3] = (_Float16)fmaxf(acc1[t][3] + hiv.w + hj3, 0.f);
        *(half4t*)&h1w[l15 * 170 + nb] = hv;
    }
    __syncthreads();

    // ---- stage 2: acc2 = W2 @ h1 (K=160, 5 chunks; W2 L2-hot, no dbuf) ----
    const float b3v = b3[0];
    floatx4 acc2[10];
    #pragma unroll
    for (int t2 = 0; t2 < 10; ++t2) acc2[t2] = (floatx4){0.f, 0.f, 0.f, 0.f};
    for (int kc2 = 0; kc2 < 5; ++kc2) {
        half8 hb = *(const half8*)&h1w[l15 * 170 + kc2 * 32 + (g4 << 3)];
        #pragma unroll
        for (int t2 = 0; t2 < 10; ++t2) {
            half8 wf = *(const half8*)(W2s16 + (size_t)(kc2 * 10 + t2) * 512 + lane * 8);
            acc2[t2] = __builtin_amdgcn_mfma_f32_16x16x32_f16(wf, hb, acc2[t2], 0, 0, 0);
        }
    }

    // ---- stage 3: s = relu(acc2 + b2) . W3, cross-k-group reduce, write ----
    float sown = 0.f;
    #pragma unroll
    for (int t2 = 0; t2 < 10; ++t2) {
        const int n2 = t2 * 16 + (g4 << 2);
        float4 bw01 = *(const float4*)&bw[n2];
        float4 bw23 = *(const float4*)&bw[n2 + 2];
        sown += fmaxf(acc2[t2][0] + bw01.x, 0.f) * bw01.y;
        sown += fmaxf(acc2[t2][1] + bw01.z, 0.f) * bw01.w;
        sown += fmaxf(acc2[t2][2] + bw23.x, 0.f) * bw23.y;
        sown += fmaxf(acc2[t2][3] + bw23.z, 0.f) * bw23.w;
    }
    float s = sown;
    s += __shfl_xor(s, 16);
    s += __shfl_xor(s, 32);
    if (lane < 16 && j < i)
        logits[(size_t)(bm + i) * M_ + j] = s + b3v;
}

// ---------------------------------------------------------------------------
// Kernel 4: loss. 1 wave/row, shuffle-only (no LDS, no barriers).
// ---------------------------------------------------------------------------
__global__ __launch_bounds__(64) void loss_kernel(
    const float* __restrict__ logits, const float* __restrict__ labels,
    float* __restrict__ out)
{
    const int bm = blockIdx.x;
    const int i  = bm & (M_ - 1);
    const int lane = threadIdx.x;

    float val[4];
    #pragma unroll
    for (int qq = 0; qq < 4; ++qq) {
        const int j = qq * 64 + lane;
        val[qq] = (j < i) ? logits[(size_t)bm * M_ + j]
                          : ((j == i) ? 0.0f : -1e30f);
    }
    float m = fmaxf(fmaxf(val[0], val[1]), fmaxf(val[2], val[3]));
    #pragma unroll
    for (int off = 32; off >= 1; off >>= 1) m = fmaxf(m, __shfl_xor(m, off));

    float s = 0.f;
    float e[4];
    #pragma unroll
    for (int qq = 0; qq < 4; ++qq) {
        const int j = qq * 64 + lane;
        e[qq] = (j <= i) ? expf(val[qq] - m) : 0.0f;
        s += e[qq];
    }
    #pragma unroll
    for (int off = 32; off >= 1; off >>= 1) s += __shfl_xor(s, off);
    const float inv_s = 1.0f / s;

    float rs = 0.f;
    #pragma unroll
    for (int qq = 0; qq < 4; ++qq) {
        const int j = qq * 64 + lane;
        float prob = (j <= i) ? (e[qq] * inv_s) : -1000.0f;
        float tv = prob * labels[(size_t)bm * M_ + j];
        rs += fminf(fmaxf(tv, 1e-8f), 1.0f - 1e-8f);
    }
    #pragma unroll
    for (int off = 32; off >= 1; off >>= 1) rs += __shfl_xor(rs, off);

    if (lane == 0) atomicAdd(out, -logf(rs));
}

// ---------------------------------------------------------------------------
extern "C" void kernel_launch(void* const* d_in, const int* in_sizes, int n_in,
                              void* d_out, int out_size, void* d_ws, size_t ws_size,
                              hipStream_t stream)
{
    const float* hidden = (const float*)d_in[0];
    const int*   sutt   = (const int*)d_in[1];
    const int*   sstart = (const int*)d_in[2];
    const int*   send   = (const int*)d_in[3];
    const float* labels = (const float*)d_in[4];
    const float* W1     = (const float*)d_in[5];
    const float* b1     = (const float*)d_in[6];
    const float* W2     = (const float*)d_in[7];
    const float* b2     = (const float*)d_in[8];
    const float* W3     = (const float*)d_in[9];
    const float* b3     = (const float*)d_in[10];

    float* ws = (float*)d_ws;
    float*    hiF     = ws;                          // [1024][160]
    float*    hjT     = ws + 163840;                 // [160][1024]
    float*    logits  = ws + 327680;                 // 262144
    float2*   bw      = (float2*)(ws + 589824);      // 160 float2
    _Float16* pooledh = (_Float16*)(ws + 590144);    // 786432 f16
    _Float16* W1cs16  = (_Float16*)(ws + 983360);    // 122880 f16
    _Float16* W2s16   = (_Float16*)(ws + 1106240);   // 25600 f16
    _Float16* W1abs   = (_Float16*)(ws + 1119040);   // 245760 f16
    _Float16* pjF16   = (_Float16*)(ws + 1241920);   // 786432 f16 (1.5 MB)
    float* out = (float*)d_out;

    hipMemsetAsync(d_out, 0, sizeof(float), stream);

    prep_pool_kernel<<<dim3(1796), 256, 0, stream>>>(
        W1, W2, b2, W3, hidden, sutt, sstart, send,
        W1cs16, W2s16, W1abs, bw, pooledh);
    hihj_kernel<<<dim3(448), 256, 0, stream>>>(pooledh, b1, W1abs,
                                               hiF, hjT, pjF16);
    pair_mlp_kernel<<<dim3(576 * B_), 256, 0, stream>>>(pooledh, pjF16, hiF, hjT,
                                                        W1cs16, W2s16, bw, b3, logits);
    loss_kernel<<<dim3(B_ * M_), 64, 0, stream>>>(logits, labels, out);
}